// Round 2
// baseline (171.982 us; speedup 1.0000x reference)
//
#include <hip/hip_runtime.h>

// out[b] = SCALE^2 * ( dot(x[b,:], colsum) + sum(bias) ),  colsum[i] = sum_o W[o,i]
// Single fused kernel with a hand-rolled grid barrier (1024 co-resident blocks):
//   Phase A: partial column sums of W (64 row-groups x 16 col-slices) + bias sum
//   Phase B: reduce 64 partials/column -> wsum (8 blocks)
//   Phase C: matvec out = SCALE2*(x . wsum + bsum), 8 rows/block
// Deterministic: no float atomics; barrier uses int atomics only.

constexpr int IN_DIM = 2048;
constexpr int BATCH  = 8192;
constexpr float SCALE2 = 0.01f;   // SCALE*SCALE
constexpr int NB = 1024;          // grid size; 4 blocks/CU * 256 CU -> all co-resident

__device__ __forceinline__ void grid_barrier(int* cnt, int* gen) {
    __syncthreads();
    if (threadIdx.x == 0) {
        __threadfence();                       // release: flush my global writes
        int g = atomicAdd(gen, 0);             // coherent read of generation
        if (atomicAdd(cnt, 1) == NB - 1) {
            atomicExch(cnt, 0);                // reset for next barrier
            __threadfence();
            atomicExch(gen, g + 1);            // release the others
        } else {
            // bounded spin: cannot hang the chip even if something goes wrong
            for (long it = 0; it < (1L << 26); ++it) {
                if (atomicAdd(gen, 0) != g) break;
                __builtin_amdgcn_s_sleep(1);
            }
        }
        __threadfence();                       // acquire: invalidate stale caches
    }
    __syncthreads();
}

__global__ __launch_bounds__(256, 4)
void fused_kernel(const float* __restrict__ x, const float* __restrict__ W,
                  const float* __restrict__ bias, float* __restrict__ out,
                  int* bar, float* bsum, float* wsum, float* partial) {
    const int t    = threadIdx.x;
    const int b    = blockIdx.x;
    const int lane = t & 63;
    const int w    = t >> 6;

    __shared__ float4 red[4][32];
    __shared__ float  bs_red[4];

    // ---------------- Phase A: partial column sums of W ----------------
    {
        const int h  = b & 15;                       // col-slice: 128 cols
        const int g  = b >> 4;                       // row-group: 32 rows
        const int c4 = (h << 7) + ((t & 31) << 2);   // this thread's 4 cols
        const int r0 = (g << 5) + (t >> 5);          // first of 4 rows (stride 8)

        float4 acc = {0.f, 0.f, 0.f, 0.f};
        #pragma unroll
        for (int k = 0; k < 4; ++k) {
            const float4 v = *reinterpret_cast<const float4*>(
                W + (size_t)(r0 + 8 * k) * IN_DIM + c4);
            acc.x += v.x; acc.y += v.y; acc.z += v.z; acc.w += v.w;
        }
        // combine lanes (t, t^32): same cols, different row subset
        acc.x += __shfl_xor(acc.x, 32);
        acc.y += __shfl_xor(acc.y, 32);
        acc.z += __shfl_xor(acc.z, 32);
        acc.w += __shfl_xor(acc.w, 32);
        if (lane < 32) red[w][lane] = acc;
        __syncthreads();
        if (w == 0 && lane < 32) {
            float4 a = red[0][lane], b1 = red[1][lane],
                   c = red[2][lane], d = red[3][lane];
            float4 s = { a.x + b1.x + c.x + d.x,
                         a.y + b1.y + c.y + d.y,
                         a.z + b1.z + c.z + d.z,
                         a.w + b1.w + c.w + d.w };
            *reinterpret_cast<float4*>(partial + (size_t)g * IN_DIM + c4) = s;
        }
    }

    // block NB-1 additionally reduces the bias vector
    if (b == NB - 1) {
        float s = 0.f;
        #pragma unroll
        for (int k = 0; k < 8; ++k) s += bias[t + (k << 8)];
        #pragma unroll
        for (int off = 32; off; off >>= 1) s += __shfl_down(s, off);
        if (lane == 0) bs_red[w] = s;
        __syncthreads();
        if (t == 0) bsum[0] = bs_red[0] + bs_red[1] + bs_red[2] + bs_red[3];
    }

    grid_barrier(bar, bar + 1);

    // ---------------- Phase B: reduce partials -> wsum ----------------
    if (b < 8) {
        const int col = (b << 8) + t;                // coalesced across threads
        float s = 0.f;
        #pragma unroll 8
        for (int g = 0; g < 64; ++g) s += partial[(size_t)g * IN_DIM + col];
        wsum[col] = s;                               // raw colsum (scale in C)
    }

    grid_barrier(bar, bar + 1);

    // ---------------- Phase C: matvec ----------------
    {
        const float bs = bsum[0];
        const int r0 = (b << 3) + (w << 1);          // 2 rows per wave
        const int r1 = r0 + 1;
        const float4* x4 = reinterpret_cast<const float4*>(x);
        const float4* w4 = reinterpret_cast<const float4*>(wsum);

        float a0 = 0.f, a1 = 0.f;
        #pragma unroll
        for (int k = 0; k < 8; ++k) {
            const float4 wv = w4[(k << 6) + lane];
            const float4 v0 = x4[(size_t)r0 * (IN_DIM / 4) + (k << 6) + lane];
            const float4 v1 = x4[(size_t)r1 * (IN_DIM / 4) + (k << 6) + lane];
            a0 += v0.x * wv.x + v0.y * wv.y + v0.z * wv.z + v0.w * wv.w;
            a1 += v1.x * wv.x + v1.y * wv.y + v1.z * wv.z + v1.w * wv.w;
        }
        #pragma unroll
        for (int off = 32; off; off >>= 1) {
            a0 += __shfl_down(a0, off);
            a1 += __shfl_down(a1, off);
        }
        if (lane == 0) {
            out[r0] = SCALE2 * (a0 + bs);
            out[r1] = SCALE2 * (a1 + bs);
        }
    }
}

extern "C" void kernel_launch(void* const* d_in, const int* in_sizes, int n_in,
                              void* d_out, int out_size, void* d_ws, size_t ws_size,
                              hipStream_t stream) {
    const float* x    = (const float*)d_in[0];   // [8192, 2048]
    const float* W    = (const float*)d_in[1];   // [2048, 2048]
    const float* bias = (const float*)d_in[2];   // [2048]
    float* out = (float*)d_out;                  // [8192]
    char*  ws  = (char*)d_ws;

    // ws layout: [0,64)   barrier cnt/gen (+pad)
    //            [64,128) bsum
    //            [128, 128+8K)   wsum[2048]
    //            [128+8K, +512K) partial[64][2048]
    int*   bar     = (int*)ws;
    float* bsum    = (float*)(ws + 64);
    float* wsum    = (float*)(ws + 128);
    float* partial = (float*)(ws + 128 + IN_DIM * sizeof(float));

    hipMemsetAsync(bar, 0, 64, stream);
    fused_kernel<<<NB, 256, 0, stream>>>(x, W, bias, out, bar, bsum, wsum, partial);
}